// Round 11
// baseline (406.860 us; speedup 1.0000x reference)
//
#include <hip/hip_runtime.h>
#include <hip/hip_bf16.h>
#include <hip/hip_cooperative_groups.h>

namespace cg = cooperative_groups;

typedef __hip_bfloat16 bf16;
typedef unsigned short ushort;

#define NN 100000
#define NE 1600000
#define NBKT 391      // ceil(NN/256) buckets of 256 dst nodes
#define BCAP 4608     // per-bucket capacity (mean 4092, sd 64, +8 sigma)
#define EPB 4096      // edges per count/place block
#define NP1 391       // ceil(NE/EPB)
#define NMT 6250      // NN/16 M-tiles for the MFMA GEMM

typedef __attribute__((ext_vector_type(8))) short s8v;   // 8 bf16 (4 VGPRs)
typedef __attribute__((ext_vector_type(4))) float f4v;   // MFMA C/D
typedef __attribute__((ext_vector_type(2))) float f2v;   // packed f32 (v_pk_add_f32)

// ---- flag-dispatched load/store: flag==1 -> f32 storage, 0 -> bf16 -------
__device__ __forceinline__ float ldf(const void* p, int i, int f32) {
    return f32 ? ((const float*)p)[i] : __bfloat162float(((const bf16*)p)[i]);
}
__device__ __forceinline__ void stf(void* p, int i, int f32, float v) {
    if (f32) ((float*)p)[i] = v;
    else     ((bf16*)p)[i] = __float2bfloat16(v);
}

// round-to-nearest-even float -> bf16 bits, and back
__device__ __forceinline__ ushort f2b(float f) {
    unsigned u = __builtin_bit_cast(unsigned, f);
    u += 0x7FFF + ((u >> 16) & 1);
    return (ushort)(u >> 16);
}
__device__ __forceinline__ float b2f(ushort h) {
    unsigned u = ((unsigned)h) << 16;
    return __builtin_bit_cast(float, u);
}
// bf16x2 dword -> two f32 (lo = bits<<16, hi = bits&0xffff0000)
__device__ __forceinline__ float blo(unsigned u) {
    return __builtin_bit_cast(float, u << 16);
}
__device__ __forceinline__ float bhi(unsigned u) {
    return __builtin_bit_cast(float, u & 0xffff0000u);
}
// unpack bf16x2 dword into a packed f32 pair (consumed by v_pk_add_f32)
__device__ __forceinline__ f2v up2(unsigned u) {
    f2v r; r.x = blo(u); r.y = bhi(u); return r;
}

__global__ void k_sentinel(unsigned* out) {
    if (threadIdx.x == 0 && blockIdx.x == 0) out[0] = 0x461C461Cu;
}

// ---------------- fused CSR build (cooperative, 391 x 512) -----------------
// All four former CSR kernels as grid-synced phases sharing one 40KB LDS
// arena: A count+detect -> B column scan -> C staged place -> D bucket sort.
// Removes 3 launches + 3 inter-kernel drains, and makes the whole CSR cost
// directly visible as one dispatch in the profile.
__global__ void __launch_bounds__(512) k_csr(
        const unsigned* __restrict__ x, int* __restrict__ flag,
        const int* __restrict__ src, const int* __restrict__ dst,
        int* __restrict__ cnt, int* __restrict__ prefT, int* __restrict__ btot,
        unsigned* __restrict__ bbuf, int* __restrict__ rowptr,
        float* __restrict__ dis, int* __restrict__ csr_off) {
    __shared__ int smem[10240];   // 40KB arena, re-carved per phase
    cg::grid_group grid = cg::this_grid();
    int b = blockIdx.x, t = threadIdx.x;
    int e0 = b * EPB;

    // ---- phase A: per-block bucket counts + dtype detect ----
    {
        int* hist = smem;                 // [0..390]
        for (int i = t; i < NBKT; i += 512) hist[i] = 0;
        __syncthreads();
        for (int k = 0; k < EPB; k += 512) {
            int e = e0 + k + t;
            if (e < NE) atomicAdd(&hist[dst[e] >> 8], 1);
        }
        __syncthreads();
        for (int i = t; i < NBKT; i += 512) cnt[b * NBKT + i] = hist[i];
        if (b == 0) {
            int* dc = smem + 512;         // [512..1023]
            int c = 0;
            for (int i = t; i < 2048; i += 512) {
                unsigned e7 = (x[i] >> 8) & 0x7F;
                c += (e7 >= 60 && e7 <= 66) ? 1 : 0;
            }
            dc[t] = c;
            __syncthreads();
            for (int s = 256; s > 0; s >>= 1) {
                if (t < s) dc[t] += dc[t + s];
                __syncthreads();
            }
            if (t == 0) *flag = (dc[0] >= 1024) ? 0 : 1;  // 1 = float32
        }
    }
    grid.sync();

    // ---- phase B: per-bucket scan over blocks (block b = bucket b) ----
    {
        int* s = smem;                    // [0..511]
        int v = (t < NP1) ? cnt[t * NBKT + b] : 0;
        s[t] = v;
        __syncthreads();
        for (int d = 1; d < 512; d <<= 1) {
            int add = (t >= d) ? s[t - d] : 0;
            __syncthreads();
            s[t] += add;
            __syncthreads();
        }
        if (t < NP1) prefT[b * NP1 + t] = s[t] - v;   // exclusive over blocks
        if (t == 511) btot[b] = s[511];
    }
    grid.sync();

    // ---- phase C: staged place into buckets (no global atomics) ----
    {
        int* base = smem;                 // [0..390]
        int* hcur = smem + 400;           // [400..790]
        int* lofs = smem + 800;           // [800..1311]
        unsigned* vals = (unsigned*)(smem + 1312);   // [1312..5407]
        int* addr = smem + 5408;          // [5408..9503]
        for (int i = t; i < NBKT; i += 512) {
            base[i] = prefT[i * NP1 + b];
            hcur[i] = 0;
        }
        __syncthreads();
        unsigned ev[8];
        int kb[8];
#pragma unroll
        for (int k = 0; k < 8; k++) {
            int e = e0 + k * 512 + t;
            if (e < NE) {
                int d = dst[e];
                ev[k] = ((unsigned)src[e] << 8) | (unsigned)(d & 255);
                kb[k] = d >> 8;
            } else kb[k] = -1;
        }
#pragma unroll
        for (int k = 0; k < 8; k++)
            if (kb[k] >= 0) atomicAdd(&hcur[kb[k]], 1);
        __syncthreads();
        int v = (t < NBKT) ? hcur[t] : 0;
        lofs[t] = v;
        __syncthreads();
        for (int d = 1; d < 512; d <<= 1) {
            int add = (t >= d) ? lofs[t - d] : 0;
            __syncthreads();
            lofs[t] += add;
            __syncthreads();
        }
        int ex = lofs[t] - v;
        __syncthreads();
        lofs[t] = ex;
        if (t < NBKT) hcur[t] = 0;        // reuse as cursor
        __syncthreads();
#pragma unroll
        for (int k = 0; k < 8; k++) {
            if (kb[k] >= 0) {
                int p = atomicAdd(&hcur[kb[k]], 1);
                int li = lofs[kb[k]] + p;
                vals[li] = ev[k];
                addr[li] = kb[k] * BCAP + base[kb[k]] + p;
            }
        }
        __syncthreads();
        int tot = min(EPB, NE - e0);
        for (int i = t; i < tot; i += 512) bbuf[addr[i]] = vals[i];
    }
    grid.sync();

    // ---- phase D: LDS counting-sort per bucket (block b = bucket b) ----
    {
        unsigned* vals = (unsigned*)smem; // [0..4607]
        int* lout = smem + 4608;          // [4608..9215]
        int* fh = smem + 9216;            // [9216..9471]
        int* fx = smem + 9472;            // [9472..9727]
        int* fc = smem + 9728;            // [9728..9983]
        // bucket base g0 = sum(btot[0..b-1]) via 512-wide reduce in lout
        int part = 0;
        for (int i = t; i < b; i += 512) part += btot[i];
        lout[t] = part;
        __syncthreads();
        for (int s = 256; s > 0; s >>= 1) {
            if (t < s) lout[t] += lout[t + s];
            __syncthreads();
        }
        int g0 = lout[0];
        int cntb = btot[b];
        if (b == 0 && t == 0) rowptr[NN] = NE;
        __syncthreads();
        const unsigned* in = bbuf + b * BCAP;
        if (t < 256) fh[t] = 0;
        __syncthreads();
        for (int i = t; i < cntb; i += 512) {
            unsigned v = in[i];
            vals[i] = v;
            atomicAdd(&fh[v & 255], 1);
        }
        __syncthreads();
        if (t < 256) fx[t] = fh[t];
        __syncthreads();
        for (int d = 1; d < 256; d <<= 1) {
            int add = (t < 256 && t >= d) ? fx[t - d] : 0;
            __syncthreads();
            if (t < 256) fx[t] += add;
            __syncthreads();
        }
        if (t < 256) {
            int n = b * 256 + t;
            int ex = fx[t] - fh[t];       // exclusive within bucket
            fc[t] = ex;
            if (n < NN) {
                rowptr[n] = g0 + ex;
                dis[n] = rsqrtf(1.0f + (float)fh[t]);
            }
        }
        __syncthreads();
        for (int i = t; i < cntb; i += 512) {
            unsigned v = vals[i];
            int p = atomicAdd(&fc[v & 255], 1);
            lout[p] = (int)((v >> 8) << 7);  // src*128 = byte offset of row
        }
        __syncthreads();
        for (int i = t; i < cntb; i += 512) csr_off[g0 + i] = lout[i];
    }
}

// ---------------- MFMA GEMM: C[N,64] = dis[row] * (A[N,64] @ W[64,64]) ----
__global__ void __launch_bounds__(256) k_gemm_mfma(
        const void* __restrict__ A, int aBase, const void* __restrict__ W,
        bf16* __restrict__ C, const float* __restrict__ dis,
        const int* __restrict__ flag) {
    int f32 = *flag;
    int t = threadIdx.x;
    // zero pad row NN (the aggregate's ZOFF target) once per GEMM launch
    if (blockIdx.x == 0 && t < 64) ((ushort*)C)[NN * 64 + t] = 0;
    int lane = t & 63;
    int w = t >> 6;
    int m = lane & 15, q = lane >> 4;

    s8v bh[2][4], bl[2][4];
#pragma unroll
    for (int st = 0; st < 2; st++)
#pragma unroll
        for (int nt = 0; nt < 4; nt++)
#pragma unroll
            for (int j = 0; j < 8; j++) {
                int k = st * 32 + q * 8 + j;
                float wv = ldf(W, k * 64 + nt * 16 + m, f32);
                ushort h = f2b(wv);
                bh[st][nt][j] = (short)h;
                bl[st][nt][j] = (short)f2b(wv - b2f(h));
            }

    ushort* Cu = (ushort*)C;
    int gw = blockIdx.x * 4 + w;
    int nw = gridDim.x * 4;
    for (int mt = gw; mt < NMT; mt += nw) {
        int row = mt * 16 + m;
        s8v ah[2], al[2];
        if (f32) {
            const float* ap = (const float*)A + aBase + row * 64 + q * 8;
#pragma unroll
            for (int st = 0; st < 2; st++) {
                f4v va = *(const f4v*)(ap + st * 32);
                f4v vb = *(const f4v*)(ap + st * 32 + 4);
#pragma unroll
                for (int j = 0; j < 8; j++) {
                    float v = (j < 4) ? va[j] : vb[j - 4];
                    ushort h = f2b(v);
                    ah[st][j] = (short)h;
                    al[st][j] = (short)f2b(v - b2f(h));
                }
            }
        } else {
            const short* ap = (const short*)A + aBase + row * 64 + q * 8;
            ah[0] = *(const s8v*)(ap);
            ah[1] = *(const s8v*)(ap + 32);
        }
        float dr[4];
#pragma unroll
        for (int r = 0; r < 4; r++) dr[r] = dis[mt * 16 + q * 4 + r];
#pragma unroll
        for (int nt = 0; nt < 4; nt++) {
            f4v acc = {0.f, 0.f, 0.f, 0.f};
#pragma unroll
            for (int st = 0; st < 2; st++)
                acc = __builtin_amdgcn_mfma_f32_16x16x32_bf16(ah[st], bh[st][nt], acc, 0, 0, 0);
            if (f32) {
#pragma unroll
                for (int st = 0; st < 2; st++) {
                    acc = __builtin_amdgcn_mfma_f32_16x16x32_bf16(ah[st], bl[st][nt], acc, 0, 0, 0);
                    acc = __builtin_amdgcn_mfma_f32_16x16x32_bf16(al[st], bh[st][nt], acc, 0, 0, 0);
                }
            }
            int col = nt * 16 + m;
#pragma unroll
            for (int r = 0; r < 4; r++) {
                int rr = mt * 16 + q * 4 + r;
                Cu[rr * 64 + col] = f2b(dr[r] * acc[r]);
            }
        }
    }
}

// ---------------- fused aggregate + bias + relu ---------------------------
// r5 structure (known 44us): one WAVE per node, persistent blocks. Lanes:
// 4 row-slots (q) x 16 feature-quads (m); uint2 gathers (4 features/lane,
// 4 rows per VMEM instr). float2 accumulators -> v_pk_add_f32. Tail slots
// redirect to the zero row bufA[NN] (written by k_gemm_mfma block 0).
__global__ void __launch_bounds__(256, 8) k_aggregate(
        const bf16* __restrict__ hs, void* hout, int hoBase,
        const float* __restrict__ dis,
        const int* __restrict__ rowptr,
        const int* __restrict__ csr_off,
        const void* __restrict__ bias,
        const int* __restrict__ flag) {
    int f32 = *flag;
    int t = threadIdx.x;
    int l = t & 63;
    int q = l >> 4;           // row slot 0..3
    int m = l & 15;           // feature quad: features 4m..4m+3
    int fb = m * 8;           // byte offset of feature quad within 128B row
    const char* hb = (const char*)hs;
    float b0 = ldf(bias, m * 4 + 0, f32);
    float b1v = ldf(bias, m * 4 + 1, f32);
    float b2v = ldf(bias, m * 4 + 2, f32);
    float b3v = ldf(bias, m * 4 + 3, f32);
    const int Z = NN * 128;   // zero-row byte offset
    int wid = blockIdx.x * 4 + (t >> 6);
    int nwav = gridDim.x * 4;
    for (int n = wid; n < NN; n += nwav) {
        int r0 = rowptr[n], r1 = rowptr[n + 1];
        f2v a01 = {0.f, 0.f}, a23 = {0.f, 0.f};
        int j = r0;
        // full groups: 16 edges, 4 gathers, zero per-edge branching
        for (; j + 16 <= r1; j += 16) {
            int o0 = csr_off[j + q];
            int o1 = csr_off[j + 4 + q];
            int o2 = csr_off[j + 8 + q];
            int o3 = csr_off[j + 12 + q];
            uint2 v0 = *(const uint2*)(hb + o0 + fb);
            uint2 v1 = *(const uint2*)(hb + o1 + fb);
            uint2 v2 = *(const uint2*)(hb + o2 + fb);
            uint2 v3 = *(const uint2*)(hb + o3 + fb);
            a01 += up2(v0.x); a23 += up2(v0.y);
            a01 += up2(v1.x); a23 += up2(v1.y);
            a01 += up2(v2.x); a23 += up2(v2.y);
            a01 += up2(v3.x); a23 += up2(v3.y);
        }
        // tail group: dead slots redirect to the zero row (csr_off reads up
        // to NE+14 land in the allocated bufA region, values discarded)
        if (j < r1) {
            int i0 = j + q, i1 = j + 4 + q, i2 = j + 8 + q, i3 = j + 12 + q;
            int o0 = csr_off[i0]; o0 = (i0 < r1) ? o0 : Z;
            int o1 = csr_off[i1]; o1 = (i1 < r1) ? o1 : Z;
            int o2 = csr_off[i2]; o2 = (i2 < r1) ? o2 : Z;
            int o3 = csr_off[i3]; o3 = (i3 < r1) ? o3 : Z;
            uint2 v0 = *(const uint2*)(hb + o0 + fb);
            uint2 v1 = *(const uint2*)(hb + o1 + fb);
            uint2 v2 = *(const uint2*)(hb + o2 + fb);
            uint2 v3 = *(const uint2*)(hb + o3 + fb);
            a01 += up2(v0.x); a23 += up2(v0.y);
            a01 += up2(v1.x); a23 += up2(v1.y);
            a01 += up2(v2.x); a23 += up2(v2.y);
            a01 += up2(v3.x); a23 += up2(v3.y);
        }
        // reduce across the 4 row slots (q): xor-32 then xor-16
        float a0 = a01.x, a1 = a01.y, a2 = a23.x, a3 = a23.y;
        a0 += __shfl_xor(a0, 32); a1 += __shfl_xor(a1, 32);
        a2 += __shfl_xor(a2, 32); a3 += __shfl_xor(a3, 32);
        a0 += __shfl_xor(a0, 16); a1 += __shfl_xor(a1, 16);
        a2 += __shfl_xor(a2, 16); a3 += __shfl_xor(a3, 16);
        if (q == 0) {
            uint2 sv = *(const uint2*)(hb + n * 128 + fb);   // self row (pre-scaled)
            float dn = dis[n];
            float o0 = fmaxf(dn * (a0 + blo(sv.x)) + b0, 0.f);
            float o1 = fmaxf(dn * (a1 + bhi(sv.x)) + b1v, 0.f);
            float o2 = fmaxf(dn * (a2 + blo(sv.y)) + b2v, 0.f);
            float o3 = fmaxf(dn * (a3 + bhi(sv.y)) + b3v, 0.f);
            if (f32) {
                float4 ov = {o0, o1, o2, o3};
                *(float4*)((float*)hout + hoBase + n * 64 + m * 4) = ov;
            } else {
                unsigned w0 = (unsigned)f2b(o0) | ((unsigned)f2b(o1) << 16);
                unsigned w1 = (unsigned)f2b(o2) | ((unsigned)f2b(o3) << 16);
                uint2 wv; wv.x = w0; wv.y = w1;
                *(uint2*)((ushort*)hout + hoBase + n * 64 + m * 4) = wv;
            }
        }
    }
}

// ---------------- head: log_softmax(h2 @ W3 + b3) -------------------------
// hrow stride padded 64->65 (stride-64 was a 16-way bank conflict on every
// inner iteration). 64 rows per block.
__global__ void k_head(const void* __restrict__ h2, int hBase,
                       const void* __restrict__ W3, const void* __restrict__ b3,
                       void* out, const int* __restrict__ flag) {
    __shared__ float w[64 * 16];
    __shared__ float hrow[64 * 65];
    int f32 = *flag;
    int t = threadIdx.x;
#pragma unroll
    for (int i = 0; i < 4; i++) w[t + i * 256] = ldf(W3, t + i * 256, f32);
    int r0 = blockIdx.x * 64;
#pragma unroll
    for (int i = 0; i < 16; i++) {
        int idx = t + i * 256;
        int row = idx >> 6;
        hrow[row * 65 + (idx & 63)] =
            (r0 + row < NN) ? ldf(h2, hBase + r0 * 64 + idx, f32) : 0.f;
    }
    __syncthreads();
    int lr = t >> 4, c = t & 15;
    float bc = ldf(b3, c, f32);
#pragma unroll
    for (int g = 0; g < 4; g++) {
        int row = lr + g * 16;
        float z = bc;
#pragma unroll
        for (int k = 0; k < 64; k++) z += hrow[row * 65 + k] * w[k * 16 + c];
        float m = z;
#pragma unroll
        for (int off = 8; off >= 1; off >>= 1) m = fmaxf(m, __shfl_xor(m, off, 16));
        float p = __expf(z - m);
        float s = p;
#pragma unroll
        for (int off = 8; off >= 1; off >>= 1) s += __shfl_xor(s, off, 16);
        if (r0 + row < NN)
            stf(out, (r0 + row) * 16 + c, f32, z - m - __logf(s));
    }
}

extern "C" void kernel_launch(void* const* d_in, const int* in_sizes, int n_in,
                              void* d_out, int out_size, void* d_ws, size_t ws_size,
                              hipStream_t stream) {
    const void* x  = d_in[0];
    const int* ei  = (const int*)d_in[1];
    const void* W1 = d_in[2];
    const void* b1 = d_in[3];
    const void* W2 = d_in[4];
    const void* b2 = d_in[5];
    const void* W3 = d_in[6];
    const void* b3 = d_in[7];

    // ws layout (4B words):
    //   0       : flag (256)
    //   256     : dis (102400)
    //   102656  : rowptr (102400, NN+1 used)
    //   205568  : btot (512, NBKT used)
    //   207104  : csr_off (NE)  -- byte offsets src*128
    //   1807104 : union { [bbuf u32[NBKT*BCAP]=1801728 | cnt 153088 | prefT 153088]
    //                     (CSR build, dead before GEMM) |
    //                     bufA bf16[(NN+1)*64] = 3200032 w }
    //             bufA row NN (bytes 12.8e6..12.8e6+128) is the zero pad row.
    const size_t NEEDED = (size_t)(1807104 + 3203072) * 4;  // ~20.05 MB (unchanged)
    if (ws_size < NEEDED) {
        k_sentinel<<<1, 64, 0, stream>>>((unsigned*)d_out);
        return;
    }
    int*      flag    = (int*)d_ws;
    float*    dis     = (float*)d_ws + 256;
    int*      rowptr  = (int*)d_ws + 102656;
    int*      btot    = (int*)d_ws + 205568;
    int*      csr_off = (int*)d_ws + 207104;
    unsigned* bbuf    = (unsigned*)((int*)d_ws + 1807104);
    int*      cnt     = (int*)d_ws + 1807104 + NBKT * BCAP;          // 3608832
    int*      prefT   = cnt + 153088;                                 // 3761920
    bf16*     bufA    = (bf16*)bbuf;   // overwrites CSR scratch after pass2

    const int* srcp = ei;
    const int* dstp = ei + NE;
    const int HB = NN * 16;   // h region starts at element NN*16 of d_out

    // ---- CSR build: single cooperative kernel (4 grid-synced phases) ------
    const unsigned* xu = (const unsigned*)x;
    void* csr_args[] = { (void*)&xu, (void*)&flag, (void*)&srcp, (void*)&dstp,
                         (void*)&cnt, (void*)&prefT, (void*)&btot, (void*)&bbuf,
                         (void*)&rowptr, (void*)&dis, (void*)&csr_off };
    hipLaunchCooperativeKernel((const void*)k_csr, dim3(NP1), dim3(512),
                               csr_args, 0, stream);

    // ---- layer 1: h1 = relu(Agg(x @ W1) + b1) ----
    k_gemm_mfma<<<1563, 256, 0, stream>>>(x, 0, W1, bufA, dis, flag);
    k_aggregate<<<2048, 256, 0, stream>>>(bufA, d_out, HB, dis, rowptr,
                                          csr_off, b1, flag);

    // ---- layer 2: h2 = relu(Agg(h1 @ W2) + b2) ----
    k_gemm_mfma<<<1563, 256, 0, stream>>>(d_out, HB, W2, bufA, dis, flag);
    k_aggregate<<<2048, 256, 0, stream>>>(bufA, d_out, HB, dis, rowptr,
                                          csr_off, b2, flag);

    // ---- head ----
    k_head<<<1563, 256, 0, stream>>>(d_out, HB, W3, b3, d_out, flag);
}

// Round 12
// 241.353 us; speedup vs baseline: 1.6857x; 1.6857x over previous
//
#include <hip/hip_runtime.h>
#include <hip/hip_bf16.h>

typedef __hip_bfloat16 bf16;
typedef unsigned short ushort;

#define NN 100000
#define NE 1600000
#define NBKT 391      // ceil(NN/256) buckets of 256 dst nodes
#define BCAP 4608     // per-bucket capacity (mean 4092, sd 64, +8 sigma)
#define EPB 4096      // edges per count/place block
#define NP1 391       // ceil(NE/EPB)
#define NMT 6250      // NN/16 M-tiles for the MFMA GEMM

typedef __attribute__((ext_vector_type(8))) short s8v;   // 8 bf16 (4 VGPRs)
typedef __attribute__((ext_vector_type(4))) float f4v;   // MFMA C/D
typedef __attribute__((ext_vector_type(2))) float f2v;   // packed f32 (v_pk_add_f32)

// ---- flag-dispatched load/store: flag==1 -> f32 storage, 0 -> bf16 -------
__device__ __forceinline__ float ldf(const void* p, int i, int f32) {
    return f32 ? ((const float*)p)[i] : __bfloat162float(((const bf16*)p)[i]);
}
__device__ __forceinline__ void stf(void* p, int i, int f32, float v) {
    if (f32) ((float*)p)[i] = v;
    else     ((bf16*)p)[i] = __float2bfloat16(v);
}

// round-to-nearest-even float -> bf16 bits, and back
__device__ __forceinline__ ushort f2b(float f) {
    unsigned u = __builtin_bit_cast(unsigned, f);
    u += 0x7FFF + ((u >> 16) & 1);
    return (ushort)(u >> 16);
}
__device__ __forceinline__ float b2f(ushort h) {
    unsigned u = ((unsigned)h) << 16;
    return __builtin_bit_cast(float, u);
}
// bf16x2 dword -> two f32 (lo = bits<<16, hi = bits&0xffff0000)
__device__ __forceinline__ float blo(unsigned u) {
    return __builtin_bit_cast(float, u << 16);
}
__device__ __forceinline__ float bhi(unsigned u) {
    return __builtin_bit_cast(float, u & 0xffff0000u);
}
// unpack bf16x2 dword into a packed f32 pair (consumed by v_pk_add_f32)
__device__ __forceinline__ f2v up2(unsigned u) {
    f2v r; r.x = blo(u); r.y = bhi(u); return r;
}

__global__ void k_sentinel(unsigned* out) {
    if (threadIdx.x == 0 && blockIdx.x == 0) out[0] = 0x461C461Cu;
}

// ---------------- CSR build A: per-block bucket counts + dtype detect ------
__global__ void k_cnt(const unsigned* __restrict__ x, int* __restrict__ flag,
                      const int* __restrict__ dst, int* __restrict__ cnt) {
    __shared__ int hist[NBKT];
    int b = blockIdx.x, t = threadIdx.x;
    for (int i = t; i < NBKT; i += 256) hist[i] = 0;
    __syncthreads();
    int e0 = b * EPB;
#pragma unroll
    for (int k = 0; k < EPB; k += 256) {
        int e = e0 + k + t;
        if (e < NE) atomicAdd(&hist[dst[e] >> 8], 1);
    }
    __syncthreads();
    for (int i = t; i < NBKT; i += 256) cnt[b * NBKT + i] = hist[i];
    if (b == 0) {
        // dtype detect on first 2048 words of x (merged launch; reuses hist)
        int c = 0;
        for (int i = t; i < 2048; i += 256) {
            unsigned e7 = (x[i] >> 8) & 0x7F;
            c += (e7 >= 60 && e7 <= 66) ? 1 : 0;
        }
        __syncthreads();
        hist[t] = c;
        __syncthreads();
        for (int s = 128; s > 0; s >>= 1) {
            if (t < s) hist[t] += hist[t + s];
            __syncthreads();
        }
        if (t == 0) *flag = (hist[0] >= 1024) ? 0 : 1;  // 1 = float32 tensors
    }
}

// ---------------- CSR build B: per-bucket scan over blocks -----------------
__global__ void k_colscan(const int* __restrict__ cnt, int* __restrict__ prefT,
                          int* __restrict__ btot) {
    __shared__ int s[512];
    int k = blockIdx.x, t = threadIdx.x;
    int v = (t < NP1) ? cnt[t * NBKT + k] : 0;
    s[t] = v;
    __syncthreads();
    for (int d = 1; d < 512; d <<= 1) {
        int add = (t >= d) ? s[t - d] : 0;
        __syncthreads();
        s[t] += add;
        __syncthreads();
    }
    if (t < NP1) prefT[k * NP1 + t] = s[t] - v;   // exclusive over blocks
    if (t == 511) btot[k] = s[511];
}

// ---------------- CSR build C: place into buckets, LDS-staged --------------
__global__ void __launch_bounds__(512) k_place(
        const int* __restrict__ src, const int* __restrict__ dst,
        const int* __restrict__ prefT, unsigned* __restrict__ bbuf) {
    __shared__ int base[NBKT];
    __shared__ int hist[NBKT];
    __shared__ int lofs[512];
    __shared__ unsigned vals[EPB];
    __shared__ int addr[EPB];
    int b = blockIdx.x, t = threadIdx.x;
    for (int i = t; i < NBKT; i += 512) {
        base[i] = prefT[i * NP1 + b];
        hist[i] = 0;
    }
    __syncthreads();
    int e0 = b * EPB;
    unsigned ev[8];
    int kb[8];
#pragma unroll
    for (int k = 0; k < 8; k++) {
        int e = e0 + k * 512 + t;
        if (e < NE) {
            int d = dst[e];
            ev[k] = ((unsigned)src[e] << 8) | (unsigned)(d & 255);
            kb[k] = d >> 8;
        } else kb[k] = -1;
    }
#pragma unroll
    for (int k = 0; k < 8; k++)
        if (kb[k] >= 0) atomicAdd(&hist[kb[k]], 1);
    __syncthreads();
    int v = (t < NBKT) ? hist[t] : 0;
    lofs[t] = v;
    __syncthreads();
    for (int d = 1; d < 512; d <<= 1) {
        int add = (t >= d) ? lofs[t - d] : 0;
        __syncthreads();
        lofs[t] += add;
        __syncthreads();
    }
    int ex = lofs[t] - v;
    __syncthreads();
    lofs[t] = ex;                       // now exclusive
    if (t < NBKT) hist[t] = 0;          // reuse as cursor
    __syncthreads();
#pragma unroll
    for (int k = 0; k < 8; k++) {
        if (kb[k] >= 0) {
            int p = atomicAdd(&hist[kb[k]], 1);
            int li = lofs[kb[k]] + p;
            vals[li] = ev[k];
            addr[li] = kb[k] * BCAP + base[kb[k]] + p;
        }
    }
    __syncthreads();
    int tot = min(EPB, NE - e0);
    for (int i = t; i < tot; i += 512) bbuf[addr[i]] = vals[i];
}

// ---------------- CSR build D: LDS counting-sort per bucket ----------------
__global__ void k_pass2(const unsigned* __restrict__ bbuf, const int* __restrict__ btot,
                        int* __restrict__ rowptr, float* __restrict__ dis,
                        int* __restrict__ csr_off) {
    __shared__ unsigned vals[BCAP];
    __shared__ int lout[BCAP];
    __shared__ int fh[256], fx[256], fc[256];
    int b = blockIdx.x, t = threadIdx.x;
    int part = 0;
    for (int i = t; i < b; i += 256) part += btot[i];
    fh[t] = part;
    __syncthreads();
    for (int s = 128; s > 0; s >>= 1) {
        if (t < s) fh[t] += fh[t + s];
        __syncthreads();
    }
    int g0 = fh[0];
    int cntb = btot[b];
    if (b == 0 && t == 0) rowptr[NN] = NE;
    __syncthreads();
    const unsigned* in = bbuf + b * BCAP;
    fh[t] = 0;
    __syncthreads();
    for (int i = t; i < cntb; i += 256) {
        unsigned v = in[i];
        vals[i] = v;
        atomicAdd(&fh[v & 255], 1);
    }
    __syncthreads();
    fx[t] = fh[t];
    __syncthreads();
    for (int d = 1; d < 256; d <<= 1) {
        int add = (t >= d) ? fx[t - d] : 0;
        __syncthreads();
        fx[t] += add;
        __syncthreads();
    }
    int n = b * 256 + t;
    int ex = fx[t] - fh[t];     // exclusive within bucket
    fc[t] = ex;
    if (n < NN) {
        rowptr[n] = g0 + ex;
        dis[n] = rsqrtf(1.0f + (float)fh[t]);
    }
    __syncthreads();
    for (int i = t; i < cntb; i += 256) {
        unsigned v = vals[i];
        int p = atomicAdd(&fc[v & 255], 1);
        lout[p] = (int)((v >> 8) << 7);   // src*128 = byte offset of bf16 row
    }
    __syncthreads();
    for (int i = t; i < cntb; i += 256) csr_off[g0 + i] = lout[i];
}

// ---------------- MFMA GEMM: C[N,64] = dis[row] * (A[N,64] @ W[64,64]) ----
// grid 512 (r7 config): ~3 tiles/wave amortizes the per-wave W-split prep.
__global__ void __launch_bounds__(256) k_gemm_mfma(
        const void* __restrict__ A, int aBase, const void* __restrict__ W,
        bf16* __restrict__ C, const float* __restrict__ dis,
        const int* __restrict__ flag) {
    int f32 = *flag;
    int t = threadIdx.x;
    // zero pad row NN (the aggregate's ZOFF target) once per GEMM launch
    if (blockIdx.x == 0 && t < 64) ((ushort*)C)[NN * 64 + t] = 0;
    int lane = t & 63;
    int w = t >> 6;
    int m = lane & 15, q = lane >> 4;

    s8v bh[2][4], bl[2][4];
#pragma unroll
    for (int st = 0; st < 2; st++)
#pragma unroll
        for (int nt = 0; nt < 4; nt++)
#pragma unroll
            for (int j = 0; j < 8; j++) {
                int k = st * 32 + q * 8 + j;
                float wv = ldf(W, k * 64 + nt * 16 + m, f32);
                ushort h = f2b(wv);
                bh[st][nt][j] = (short)h;
                bl[st][nt][j] = (short)f2b(wv - b2f(h));
            }

    ushort* Cu = (ushort*)C;
    int gw = blockIdx.x * 4 + w;
    int nw = gridDim.x * 4;
    for (int mt = gw; mt < NMT; mt += nw) {
        int row = mt * 16 + m;
        s8v ah[2], al[2];
        if (f32) {
            const float* ap = (const float*)A + aBase + row * 64 + q * 8;
#pragma unroll
            for (int st = 0; st < 2; st++) {
                f4v va = *(const f4v*)(ap + st * 32);
                f4v vb = *(const f4v*)(ap + st * 32 + 4);
#pragma unroll
                for (int j = 0; j < 8; j++) {
                    float v = (j < 4) ? va[j] : vb[j - 4];
                    ushort h = f2b(v);
                    ah[st][j] = (short)h;
                    al[st][j] = (short)f2b(v - b2f(h));
                }
            }
        } else {
            const short* ap = (const short*)A + aBase + row * 64 + q * 8;
            ah[0] = *(const s8v*)(ap);
            ah[1] = *(const s8v*)(ap + 32);
        }
        float dr[4];
#pragma unroll
        for (int r = 0; r < 4; r++) dr[r] = dis[mt * 16 + q * 4 + r];
#pragma unroll
        for (int nt = 0; nt < 4; nt++) {
            f4v acc = {0.f, 0.f, 0.f, 0.f};
#pragma unroll
            for (int st = 0; st < 2; st++)
                acc = __builtin_amdgcn_mfma_f32_16x16x32_bf16(ah[st], bh[st][nt], acc, 0, 0, 0);
            if (f32) {
#pragma unroll
                for (int st = 0; st < 2; st++) {
                    acc = __builtin_amdgcn_mfma_f32_16x16x32_bf16(ah[st], bl[st][nt], acc, 0, 0, 0);
                    acc = __builtin_amdgcn_mfma_f32_16x16x32_bf16(al[st], bh[st][nt], acc, 0, 0, 0);
                }
            }
            int col = nt * 16 + m;
#pragma unroll
            for (int r = 0; r < 4; r++) {
                int rr = mt * 16 + q * 4 + r;
                Cu[rr * 64 + col] = f2b(dr[r] * acc[r]);
            }
        }
    }
}

// ---------------- fused aggregate + bias + relu (+ optional head) ----------
// r7 structure (best measured total, 251.7): MODE==1 keeps W3 in an LDS tile
// (NOT registers -- r8's register variant rematerialized 16 global loads per
// node under the VGPR=32 cap), but the tile is now PADDED to stride 17:
// the old stride-16 put all 16 m-lanes of a quad 256B apart -> same bank ->
// 16-way conflict (917K cycles). Stride 17 -> banks (4m)%32: 8 banks x 2
// lanes = 2-way, which is free (m136). expf/logf -> __expf/__logf (hw
// v_exp/v_log, no register-pressure effect).
template<int MODE>
__global__ void __launch_bounds__(256, 8) k_aggregate(
        const bf16* __restrict__ hs, void* hout, int hoBase,
        const float* __restrict__ dis,
        const int* __restrict__ rowptr,
        const int* __restrict__ csr_off,
        const void* __restrict__ bias,
        const int* __restrict__ flag,
        const void* __restrict__ W3, const void* __restrict__ b3,
        void* __restrict__ lgout) {
    __shared__ float w3s[MODE ? 64 * 17 : 1];     // padded stride 17
    int f32 = *flag;
    int t = threadIdx.x;
    int l = t & 63;
    int q = l >> 4;           // row slot 0..3 (also head class-quad)
    int m = l & 15;           // feature quad: features 4m..4m+3
    int fb = m * 8;           // byte offset of feature quad within 128B row
    const char* hb = (const char*)hs;
    float b0 = ldf(bias, m * 4 + 0, f32);
    float b1v = ldf(bias, m * 4 + 1, f32);
    float b2v = ldf(bias, m * 4 + 2, f32);
    float b3v = ldf(bias, m * 4 + 3, f32);
    float hb3[4];
    if constexpr (MODE == 1) {
        for (int i = t; i < 1024; i += 256)
            w3s[(i >> 4) * 17 + (i & 15)] = ldf(W3, i, f32);
#pragma unroll
        for (int j2 = 0; j2 < 4; j2++) hb3[j2] = ldf(b3, q * 4 + j2, f32);
        __syncthreads();
    }
    const int Z = NN * 128;   // zero-row byte offset
    int wid = blockIdx.x * 4 + (t >> 6);
    int nwav = gridDim.x * 4;
    for (int n = wid; n < NN; n += nwav) {
        int r0 = rowptr[n], r1 = rowptr[n + 1];
        f2v a01 = {0.f, 0.f}, a23 = {0.f, 0.f};
        int j = r0;
        // full groups: 16 edges, 4 gathers, zero per-edge branching
        for (; j + 16 <= r1; j += 16) {
            int o0 = csr_off[j + q];
            int o1 = csr_off[j + 4 + q];
            int o2 = csr_off[j + 8 + q];
            int o3 = csr_off[j + 12 + q];
            uint2 v0 = *(const uint2*)(hb + o0 + fb);
            uint2 v1 = *(const uint2*)(hb + o1 + fb);
            uint2 v2 = *(const uint2*)(hb + o2 + fb);
            uint2 v3 = *(const uint2*)(hb + o3 + fb);
            a01 += up2(v0.x); a23 += up2(v0.y);
            a01 += up2(v1.x); a23 += up2(v1.y);
            a01 += up2(v2.x); a23 += up2(v2.y);
            a01 += up2(v3.x); a23 += up2(v3.y);
        }
        // tail group: dead slots redirect to the zero row (csr_off reads up
        // to NE+14 land in the allocated bufA region, values discarded)
        if (j < r1) {
            int i0 = j + q, i1 = j + 4 + q, i2 = j + 8 + q, i3 = j + 12 + q;
            int o0 = csr_off[i0]; o0 = (i0 < r1) ? o0 : Z;
            int o1 = csr_off[i1]; o1 = (i1 < r1) ? o1 : Z;
            int o2 = csr_off[i2]; o2 = (i2 < r1) ? o2 : Z;
            int o3 = csr_off[i3]; o3 = (i3 < r1) ? o3 : Z;
            uint2 v0 = *(const uint2*)(hb + o0 + fb);
            uint2 v1 = *(const uint2*)(hb + o1 + fb);
            uint2 v2 = *(const uint2*)(hb + o2 + fb);
            uint2 v3 = *(const uint2*)(hb + o3 + fb);
            a01 += up2(v0.x); a23 += up2(v0.y);
            a01 += up2(v1.x); a23 += up2(v1.y);
            a01 += up2(v2.x); a23 += up2(v2.y);
            a01 += up2(v3.x); a23 += up2(v3.y);
        }
        // reduce across the 4 row slots (q): xor-32 then xor-16
        float a0 = a01.x, a1 = a01.y, a2 = a23.x, a3 = a23.y;
        a0 += __shfl_xor(a0, 32); a1 += __shfl_xor(a1, 32);
        a2 += __shfl_xor(a2, 32); a3 += __shfl_xor(a3, 32);
        a0 += __shfl_xor(a0, 16); a1 += __shfl_xor(a1, 16);
        a2 += __shfl_xor(a2, 16); a3 += __shfl_xor(a3, 16);
        if constexpr (MODE == 0) {
            if (q == 0) {
                uint2 sv = *(const uint2*)(hb + n * 128 + fb);  // self row
                float dn = dis[n];
                float o0 = fmaxf(dn * (a0 + blo(sv.x)) + b0, 0.f);
                float o1 = fmaxf(dn * (a1 + bhi(sv.x)) + b1v, 0.f);
                float o2 = fmaxf(dn * (a2 + blo(sv.y)) + b2v, 0.f);
                float o3 = fmaxf(dn * (a3 + bhi(sv.y)) + b3v, 0.f);
                if (f32) {
                    float4 ov = {o0, o1, o2, o3};
                    *(float4*)((float*)hout + hoBase + n * 64 + m * 4) = ov;
                } else {
                    unsigned w0 = (unsigned)f2b(o0) | ((unsigned)f2b(o1) << 16);
                    unsigned w1 = (unsigned)f2b(o2) | ((unsigned)f2b(o3) << 16);
                    uint2 wv; wv.x = w0; wv.y = w1;
                    *(uint2*)((ushort*)hout + hoBase + n * 64 + m * 4) = wv;
                }
            }
        } else {
            // ALL lanes finish the row (head needs every lane's o0..o3)
            uint2 sv = *(const uint2*)(hb + n * 128 + fb);
            float dn = dis[n];
            float o0 = fmaxf(dn * (a0 + blo(sv.x)) + b0, 0.f);
            float o1 = fmaxf(dn * (a1 + bhi(sv.x)) + b1v, 0.f);
            float o2 = fmaxf(dn * (a2 + blo(sv.y)) + b2v, 0.f);
            float o3 = fmaxf(dn * (a3 + bhi(sv.y)) + b3v, 0.f);
            if (q == 0) {
                if (f32) {
                    float4 ov = {o0, o1, o2, o3};
                    *(float4*)((float*)hout + hoBase + n * 64 + m * 4) = ov;
                } else {
                    unsigned w0 = (unsigned)f2b(o0) | ((unsigned)f2b(o1) << 16);
                    unsigned w1 = (unsigned)f2b(o2) | ((unsigned)f2b(o3) << 16);
                    uint2 wv; wv.x = w0; wv.y = w1;
                    *(uint2*)((ushort*)hout + hoBase + n * 64 + m * 4) = wv;
                }
            }
            // head partials: this lane's 4 feats (m*4+i) x 4 classes (q*4+j)
            float z0 = 0.f, z1 = 0.f, z2 = 0.f, z3 = 0.f;
            float oo[4] = {o0, o1, o2, o3};
#pragma unroll
            for (int i = 0; i < 4; i++) {
                float4 wv = *(const float4*)(w3s + (m * 4 + i) * 17 + q * 4);
                z0 += oo[i] * wv.x; z1 += oo[i] * wv.y;
                z2 += oo[i] * wv.z; z3 += oo[i] * wv.w;
            }
            // sum over the 16 m-lanes (bits 0-3)
#pragma unroll
            for (int msk = 1; msk <= 8; msk <<= 1) {
                z0 += __shfl_xor(z0, msk); z1 += __shfl_xor(z1, msk);
                z2 += __shfl_xor(z2, msk); z3 += __shfl_xor(z3, msk);
            }
            z0 += hb3[0]; z1 += hb3[1]; z2 += hb3[2]; z3 += hb3[3];
            // log_softmax across 16 classes (quads live on lane bits 4-5)
            float M = fmaxf(fmaxf(z0, z1), fmaxf(z2, z3));
            M = fmaxf(M, __shfl_xor(M, 16));
            M = fmaxf(M, __shfl_xor(M, 32));
            float es = __expf(z0 - M) + __expf(z1 - M)
                     + __expf(z2 - M) + __expf(z3 - M);
            es += __shfl_xor(es, 16);
            es += __shfl_xor(es, 32);
            float ls = __logf(es) + M;
            if (m == 0) {
                if (f32) {
                    float4 ov = {z0 - ls, z1 - ls, z2 - ls, z3 - ls};
                    *(float4*)((float*)lgout + n * 16 + q * 4) = ov;
                } else {
                    unsigned p0 = (unsigned)f2b(z0 - ls) | ((unsigned)f2b(z1 - ls) << 16);
                    unsigned p1 = (unsigned)f2b(z2 - ls) | ((unsigned)f2b(z3 - ls) << 16);
                    uint2 pv; pv.x = p0; pv.y = p1;
                    *(uint2*)((ushort*)lgout + n * 16 + q * 4) = pv;
                }
            }
        }
    }
}

extern "C" void kernel_launch(void* const* d_in, const int* in_sizes, int n_in,
                              void* d_out, int out_size, void* d_ws, size_t ws_size,
                              hipStream_t stream) {
    const void* x  = d_in[0];
    const int* ei  = (const int*)d_in[1];
    const void* W1 = d_in[2];
    const void* b1 = d_in[3];
    const void* W2 = d_in[4];
    const void* b2 = d_in[5];
    const void* W3 = d_in[6];
    const void* b3 = d_in[7];

    // ws layout (4B words):
    //   0       : flag (256)
    //   256     : dis (102400)
    //   102656  : rowptr (102400, NN+1 used)
    //   205568  : btot (512, NBKT used)
    //   207104  : csr_off (NE)  -- byte offsets src*128
    //   1807104 : union { [bbuf u32[NBKT*BCAP]=1801728 | cnt 153088 | prefT 153088]
    //                     (CSR build, dead before GEMM) |
    //                     bufA bf16[(NN+1)*64] = 3200032 w }
    //             bufA row NN (bytes 12.8e6..12.8e6+128) is the zero pad row.
    const size_t NEEDED = (size_t)(1807104 + 3203072) * 4;  // ~20.05 MB (unchanged)
    if (ws_size < NEEDED) {
        k_sentinel<<<1, 64, 0, stream>>>((unsigned*)d_out);
        return;
    }
    int*      flag    = (int*)d_ws;
    float*    dis     = (float*)d_ws + 256;
    int*      rowptr  = (int*)d_ws + 102656;
    int*      btot    = (int*)d_ws + 205568;
    int*      csr_off = (int*)d_ws + 207104;
    unsigned* bbuf    = (unsigned*)((int*)d_ws + 1807104);
    int*      cnt     = (int*)d_ws + 1807104 + NBKT * BCAP;          // 3608832
    int*      prefT   = cnt + 153088;                                 // 3761920
    bf16*     bufA    = (bf16*)bbuf;   // overwrites CSR scratch after pass2

    const int* srcp = ei;
    const int* dstp = ei + NE;
    const int HB = NN * 16;   // h region starts at element NN*16 of d_out

    // ---- CSR build: count+detect -> column scan -> place -> sort ----------
    k_cnt<<<NP1, 256, 0, stream>>>((const unsigned*)x, flag, dstp, cnt);
    k_colscan<<<NBKT, 512, 0, stream>>>(cnt, prefT, btot);
    k_place<<<NP1, 512, 0, stream>>>(srcp, dstp, prefT, bbuf);
    k_pass2<<<NBKT, 256, 0, stream>>>(bbuf, btot, rowptr, dis, csr_off);

    // ---- layer 1: h1 = relu(Agg(x @ W1) + b1) ----
    k_gemm_mfma<<<512, 256, 0, stream>>>(x, 0, W1, bufA, dis, flag);
    k_aggregate<0><<<2048, 256, 0, stream>>>(bufA, d_out, HB, dis, rowptr,
                                             csr_off, b1, flag,
                                             nullptr, nullptr, nullptr);

    // ---- layer 2: h2 = relu(Agg(h1 @ W2) + b2), head fused ----
    k_gemm_mfma<<<512, 256, 0, stream>>>(d_out, HB, W2, bufA, dis, flag);
    k_aggregate<1><<<2048, 256, 0, stream>>>(bufA, d_out, HB, dis, rowptr,
                                             csr_off, b2, flag,
                                             W3, b3, d_out);
}